// Round 18
// baseline (170.833 us; speedup 1.0000x reference)
//
#include <hip/hip_runtime.h>
#include <hip/hip_fp16.h>
#include <math.h>

#define N_IN_CH 256
#define N_OUT   256   // HEADS * OUT_CH
#define HEADS   4
#define OUT_CH  64
#define BM      64    // rows per proj block (two halves of HM)
#define HM      32    // half-tile rows -> 16KB LDS, 32 AGPR
#define SCAN_BLOCK 1024

typedef __attribute__((ext_vector_type(8))) short bf16x8;
typedef __attribute__((ext_vector_type(4))) float f32x4;

__device__ __forceinline__ float lrelu(float a) {
  return a >= 0.f ? a : 0.2f * a;
}

__device__ __forceinline__ ushort f2bf(float f) {
  uint u = __float_as_uint(f);
  uint r = (u + 0x7FFFu + ((u >> 16) & 1u)) >> 16;
  return (ushort)r;
}

__device__ __forceinline__ ushort f2h(float f) {
  return __half_as_ushort(__float2half(f));
}
__device__ __forceinline__ float h2f(ushort u) {
  return __half2float(__ushort_as_half(u));
}

// wave-level exclusive scan of partials[0..nparts) -> per-lane excl value
__device__ __forceinline__ int wave_scan_partials(const int* __restrict__ partials,
                                                  int nparts, int lane) {
  int pv = (lane < nparts) ? partials[lane] : 0;
  int incl = pv;
#pragma unroll
  for (int d = 1; d < 64; d <<= 1) {
    int t = __shfl_up(incl, d, 64);
    if (lane >= d) incl += t;
  }
  return incl - pv;
}

// -------- Kernel W: weight [H][K][C] fp32 -> Bt [N][K] bf16; zero counts ----
__global__ void convert_w(const float* __restrict__ w, ushort* __restrict__ bt,
                          int* __restrict__ counts, int nnodes) {
  const int idx = blockIdx.x * 256 + threadIdx.x;  // 0..65535
  if (idx < nnodes) counts[idx] = 0;
  const int n = idx >> 8, k = idx & 255;
  const int h = n >> 6, c = n & 63;
  bt[idx] = f2bf(w[h * (N_IN_CH * OUT_CH) + k * OUT_CH + c]);
}

// ---- Kernel A: INTERLEAVED heterogeneous proj || count ---------------------
// R15's winning structure, count path now FIRE-AND-FORGET: the atomic's return
// value is unused, so the wave never waits on the ~700ns device-scope round
// trip (R17 refuted contention; the cost signature is latency exposure at this
// kernel's 15% occupancy). Rank acquisition moved to scatter (full occupancy).
__global__ __launch_bounds__(256) void proj_count(
    const float* __restrict__ x, const ushort* __restrict__ bt,
    const float* __restrict__ att_src, const float* __restrict__ att_dst,
    ushort* __restrict__ xh, float* __restrict__ asrc, float* __restrict__ adst,
    int nnodes, int nblocksA,
    const int* __restrict__ row, int* __restrict__ counts, int nedges) {
  __shared__ ushort at[HM * N_IN_CH];  // 16 KB (proj path only)
  const int tid = threadIdx.x;
  const int bid = blockIdx.x;
  const int g = bid / 5;
  const bool is_proj = (bid % 5 == 0) && (g < nblocksA);

  if (!is_proj) {  // ---- count path: 4k + (bid%5) - 1, bijective 0..eblk-1 --
    const int cb = (bid % 5 == 0) ? (4 * g)  // only when g >= nblocksA (tail)
                                  : (4 * g + (bid % 5) - 1);
    const int e = cb * 256 + tid;
    if (e < nedges) atomicAdd(&counts[row[e]], 1);  // no return used
    return;
  }

  // ---- proj path: two 32-row halves sharing the 16KB LDS buffer ----
  const int wave = tid >> 6;
  const int lane = tid & 63;
  const int lmod = lane & 15;
  const int ldiv = lane >> 4;

  float atts[4], attd[4];
#pragma unroll
  for (int nt = 0; nt < 4; ++nt) {
    const int gcol = wave * 64 + nt * 16 + lmod;
    atts[nt] = att_src[gcol];
    attd[nt] = att_dst[gcol];
  }

  for (int h0 = 0; h0 < 2; ++h0) {
    const int n0 = g * BM + h0 * HM;

    {
      const int rsub = tid >> 6;
      const int cf = (tid & 63) * 4;
      const int cb2 = cf * 2;
#pragma unroll
      for (int it = 0; it < 8; ++it) {
        const int lr = it * 4 + rsub;          // local row 0..31
        const int grow = n0 + lr;
        float4 xv = make_float4(0.f, 0.f, 0.f, 0.f);
        if (grow < nnodes) xv = *(const float4*)&x[(size_t)grow * N_IN_CH + cf];
        ushort4 b;
        b.x = f2bf(xv.x); b.y = f2bf(xv.y); b.z = f2bf(xv.z); b.w = f2bf(xv.w);
        const int cbs = cb2 ^ ((lr & 7) << 4);
        *(ushort4*)((char*)at + lr * 512 + cbs) = b;
      }
    }
    __syncthreads();

    f32x4 acc[2][4];
#pragma unroll
    for (int mt = 0; mt < 2; ++mt)
#pragma unroll
      for (int nt = 0; nt < 4; ++nt) acc[mt][nt] = (f32x4){0.f, 0.f, 0.f, 0.f};

    for (int ks = 0; ks < 8; ++ks) {
      bf16x8 a[2], b[4];
#pragma unroll
      for (int mt = 0; mt < 2; ++mt) {
        const int lr = mt * 16 + lmod;
        const int kb = ks * 64 + ldiv * 16;
        const int cbs = kb ^ ((lr & 7) << 4);
        a[mt] = *(const bf16x8*)((const char*)at + lr * 512 + cbs);
      }
#pragma unroll
      for (int nt = 0; nt < 4; ++nt) {
        const int n = wave * 64 + nt * 16 + lmod;
        b[nt] = *(const bf16x8*)&bt[(size_t)n * N_IN_CH + ks * 32 + ldiv * 8];
      }
#pragma unroll
      for (int mt = 0; mt < 2; ++mt)
#pragma unroll
        for (int nt = 0; nt < 4; ++nt)
          acc[mt][nt] = __builtin_amdgcn_mfma_f32_16x16x32_bf16(
              a[mt], b[nt], acc[mt][nt], 0, 0, 0);
    }

#pragma unroll
    for (int mt = 0; mt < 2; ++mt) {
#pragma unroll
      for (int reg = 0; reg < 4; ++reg) {
        const int grow = n0 + mt * 16 + ldiv * 4 + reg;  // C/D row=(lane>>4)*4+reg
        const bool ok = grow < nnodes;
        float vs = 0.f, vd = 0.f;
#pragma unroll
        for (int nt = 0; nt < 4; ++nt) {
          const float v = acc[mt][nt][reg];
          if (ok) xh[(size_t)grow * N_OUT + wave * 64 + nt * 16 + lmod] = f2h(v);
          vs = fmaf(v, atts[nt], vs);
          vd = fmaf(v, attd[nt], vd);
        }
#pragma unroll
        for (int d = 1; d < 16; d <<= 1) {
          vs += __shfl_xor(vs, d, 64);
          vd += __shfl_xor(vd, d, 64);
        }
        if (lmod == 0 && ok) {
          asrc[grow * HEADS + wave] = vs;
          adst[grow * HEADS + wave] = vd;
        }
      }
    }
    __syncthreads();  // LDS reused by next half
  }
}

// -- scan1: block-local exclusive scan; also seeds cursor = offsets ----------
__global__ __launch_bounds__(SCAN_BLOCK) void scan1_kernel(
    const int* __restrict__ counts, int* __restrict__ offsets,
    int* __restrict__ cursor, int* __restrict__ partials, int n) {
  __shared__ int wsum[16];
  const int tid = threadIdx.x;
  const int lane = tid & 63;
  const int wid = tid >> 6;
  const int i = blockIdx.x * SCAN_BLOCK + tid;
  int v = (i < n) ? counts[i] : 0;
  int incl = v;
#pragma unroll
  for (int d = 1; d < 64; d <<= 1) {
    int t = __shfl_up(incl, d, 64);
    if (lane >= d) incl += t;
  }
  if (lane == 63) wsum[wid] = incl;
  __syncthreads();
  if (wid == 0) {
    int wv = (lane < 16) ? wsum[lane] : 0;
#pragma unroll
    for (int d = 1; d < 16; d <<= 1) {
      int t = __shfl_up(wv, d, 64);
      if (lane >= d) wv += t;
    }
    if (lane < 16) wsum[lane] = wv;
  }
  __syncthreads();
  const int wexcl = (wid == 0) ? 0 : wsum[wid - 1];
  const int val = wexcl + incl - v;
  if (i <= n) offsets[i] = val;
  if (i < n) cursor[i] = val;   // block-local base; scatter adds partials term
  if (tid == SCAN_BLOCK - 1) partials[blockIdx.x] = wsum[15];
}

// -- scatter: atomic cursor (rank acquired HERE at full occupancy) -----------
// One 800k atomic-with-return pass, but in a kernel with no LDS, ~20 VGPR,
// full wave occupancy -> the ~700ns return latency is TLP-hidden.
__global__ void scatter_kernel(const int* __restrict__ row, const int* __restrict__ col,
                               int* __restrict__ cursor,
                               const int* __restrict__ partials, int nparts,
                               const float* __restrict__ asrc,
                               const float* __restrict__ adst,
                               uint4* __restrict__ erec, int nedges) {
  const int lane = threadIdx.x & 63;
  const int excl = wave_scan_partials(partials, nparts, lane);
  int e = blockIdx.x * blockDim.x + threadIdx.x;
  if (e < nedges) {
    const int r = row[e];
    const int c = col[e];
    const int pos = atomicAdd(&cursor[r], 1) + __shfl(excl, r >> 10, 64);
    const float4 s = *(const float4*)&asrc[r * 4];
    const float4 d = *(const float4*)&adst[c * 4];
    uint4 rec;
    rec.x = (uint)c;
    rec.y = (uint)f2h(__expf(lrelu(s.x + d.x))) |
            ((uint)f2h(__expf(lrelu(s.y + d.y))) << 16);
    rec.z = (uint)f2h(__expf(lrelu(s.z + d.z))) |
            ((uint)f2h(__expf(lrelu(s.w + d.w))) << 16);
    rec.w = 0u;
    erec[pos] = rec;
  }
}

// ------- gather: denominator folded into the weight reads (no shfl tree) ----
__global__ __launch_bounds__(256) void gather_kernel(
    const int* __restrict__ offsets,
    const int* __restrict__ partials, int nparts,
    const uint4* __restrict__ erec,
    const ushort* __restrict__ xh, const float* __restrict__ bias,
    float* __restrict__ out, int nnodes) {
  __shared__ float pbuf[4][64 * 4];
  const int wv = threadIdx.x >> 6;
  const int lane = threadIdx.x & 63;
  const int n = blockIdx.x * 4 + wv;
  if (n >= nnodes) return;
  const int excl = wave_scan_partials(partials, nparts, lane);
  const int off = offsets[n] + __shfl(excl, n >> 10, 64);
  const int end = offsets[n + 1] + __shfl(excl, (n + 1) >> 10, 64);
  const int deg = end - off;
  const int half = lane >> 5;        // 0: even edges, 1: odd edges
  const int ch8 = (lane & 31) * 8;   // this lane's 8 output channels
  const int hh = (lane & 31) >> 3;   // head owning those channels

  float wsum = 0.f;
  float a0 = 0.f, a1 = 0.f, a2 = 0.f, a3 = 0.f;
  float a4 = 0.f, a5 = 0.f, a6 = 0.f, a7 = 0.f;

  for (int b = 0; b < deg; b += 64) {
    const int cnt = min(64, deg - b);
    // one coalesced 16B load: source id + 4 precomputed f16 weights
    int cl_l = 0;
    float4 p = make_float4(0.f, 0.f, 0.f, 0.f);
    if (lane < cnt) {
      const uint4 rec = erec[off + b + lane];
      cl_l = (int)rec.x;
      p.x = h2f((ushort)(rec.y & 0xFFFFu));
      p.y = h2f((ushort)(rec.y >> 16));
      p.z = h2f((ushort)(rec.z & 0xFFFFu));
      p.w = h2f((ushort)(rec.z >> 16));
    }
    *(float4*)&pbuf[wv][lane * 4] = p;
    // same-wave LDS write->read ordered via lgkmcnt (no barrier needed)

    for (int j = 0; j < cnt; j += 16) {
      // distribute addresses via shuffles, issue payload loads immediately.
      // invalid tail slots carry cl=0 (safe read) and weight 0.
      int cq[8];
#pragma unroll
      for (int q = 0; q < 8; ++q) cq[q] = __shfl(cl_l, j + 2 * q + half, 64);
      uint4 xq[8];
#pragma unroll
      for (int q = 0; q < 8; ++q)
        xq[q] = *(const uint4*)&xh[(size_t)cq[q] * N_OUT + ch8];

      float wq[8];
#pragma unroll
      for (int q = 0; q < 8; ++q) wq[q] = pbuf[wv][(j + 2 * q + half) * 4 + hh];

#pragma unroll
      for (int q = 0; q < 8; ++q) {
        wsum += wq[q];
        a0 = fmaf(wq[q], h2f((ushort)(xq[q].x & 0xFFFFu)), a0);
        a1 = fmaf(wq[q], h2f((ushort)(xq[q].x >> 16)), a1);
        a2 = fmaf(wq[q], h2f((ushort)(xq[q].y & 0xFFFFu)), a2);
        a3 = fmaf(wq[q], h2f((ushort)(xq[q].y >> 16)), a3);
        a4 = fmaf(wq[q], h2f((ushort)(xq[q].z & 0xFFFFu)), a4);
        a5 = fmaf(wq[q], h2f((ushort)(xq[q].z >> 16)), a5);
        a6 = fmaf(wq[q], h2f((ushort)(xq[q].w & 0xFFFFu)), a6);
        a7 = fmaf(wq[q], h2f((ushort)(xq[q].w >> 16)), a7);
      }
    }
  }

  // combine the two edge-halves (both halves end with the full sums)
  a0 += __shfl_xor(a0, 32, 64);
  a1 += __shfl_xor(a1, 32, 64);
  a2 += __shfl_xor(a2, 32, 64);
  a3 += __shfl_xor(a3, 32, 64);
  a4 += __shfl_xor(a4, 32, 64);
  a5 += __shfl_xor(a5, 32, 64);
  a6 += __shfl_xor(a6, 32, 64);
  a7 += __shfl_xor(a7, 32, 64);
  wsum += __shfl_xor(wsum, 32, 64);

  const float invh = 1.f / fmaxf(wsum, 1e-16f);

  // each half writes 4 of the lane's 8 channels (fully coalesced 256 floats)
  const int wch = ch8 + half * 4;
  const float4 b4 = *(const float4*)&bias[wch];
  float4 o;
  o.x = fmaf(half ? a4 : a0, invh, b4.x);
  o.y = fmaf(half ? a5 : a1, invh, b4.y);
  o.z = fmaf(half ? a6 : a2, invh, b4.z);
  o.w = fmaf(half ? a7 : a3, invh, b4.w);
  *(float4*)&out[(size_t)n * N_OUT + wch] = o;
}

extern "C" void kernel_launch(void* const* d_in, const int* in_sizes, int n_in,
                              void* d_out, int out_size, void* d_ws, size_t ws_size,
                              hipStream_t stream) {
  const float* x        = (const float*)d_in[0];
  const int*   edge_idx = (const int*)d_in[1];
  const float* weight   = (const float*)d_in[2];
  const float* att_src  = (const float*)d_in[3];
  const float* att_dst  = (const float*)d_in[4];
  const float* bias     = (const float*)d_in[5];
  float* out = (float*)d_out;

  const int nnodes = in_sizes[0] / N_IN_CH;
  const int nedges = in_sizes[1] / 2;
  const int* row = edge_idx;            // destinations (segment index)
  const int* col = edge_idx + nedges;   // sources (features gathered)

  char* wsb = (char*)d_ws;
  size_t woff = 0;
  auto alloc = [&](size_t bytes) -> char* {
    char* p = wsb + woff;
    woff += (bytes + 255) & ~(size_t)255;
    return p;
  };
  ushort* xh    = (ushort*)alloc((size_t)nnodes * N_OUT * sizeof(ushort));
  ushort* bt    = (ushort*)alloc((size_t)N_OUT * N_IN_CH * sizeof(ushort));
  float* asrc   = (float*)alloc((size_t)nnodes * HEADS * sizeof(float));
  float* adst   = (float*)alloc((size_t)nnodes * HEADS * sizeof(float));
  int* counts   = (int*)alloc((size_t)nnodes * sizeof(int));
  int* offsets  = (int*)alloc((size_t)(nnodes + 1) * sizeof(int));
  int* cursor   = (int*)alloc((size_t)nnodes * sizeof(int));
  int* partials = (int*)alloc(256 * sizeof(int));
  uint4* erec   = (uint4*)alloc((size_t)nedges * sizeof(uint4));

  convert_w<<<256, 256, 0, stream>>>(weight, bt, counts, nnodes);

  const int eblocks = (nedges + 255) / 256;                        // 3125
  const int nblocksA = (nnodes + BM - 1) / BM;                     // 782
  const int total = nblocksA + eblocks;                            // 3907
  proj_count<<<total, 256, 0, stream>>>(
      x, bt, att_src, att_dst, xh, asrc, adst, nnodes, nblocksA,
      row, counts, nedges);

  const int nscan = (nnodes + 1 + SCAN_BLOCK - 1) / SCAN_BLOCK;    // 49
  scan1_kernel<<<nscan, SCAN_BLOCK, 0, stream>>>(counts, offsets, cursor,
                                                 partials, nnodes);

  scatter_kernel<<<eblocks, 256, 0, stream>>>(row, col, cursor,
                                              partials, nscan,
                                              asrc, adst, erec, nedges);

  gather_kernel<<<(nnodes + 3) / 4, 256, 0, stream>>>(offsets, partials, nscan,
                                                      erec, xh, bias, out, nnodes);
}

// Round 19
// 154.505 us; speedup vs baseline: 1.1057x; 1.1057x over previous
//
#include <hip/hip_runtime.h>
#include <hip/hip_fp16.h>
#include <math.h>

#define N_IN_CH 256
#define N_OUT   256   // HEADS * OUT_CH
#define HEADS   4
#define OUT_CH  64
#define BM      64    // rows per proj block (two halves of HM)
#define HM      32    // half-tile rows -> 16KB LDS, 32 AGPR
#define NXCD    8
#define SCAN_BLOCK 1024

typedef __attribute__((ext_vector_type(8))) short bf16x8;
typedef __attribute__((ext_vector_type(4))) float f32x4;

__device__ __forceinline__ float lrelu(float a) {
  return a >= 0.f ? a : 0.2f * a;
}

__device__ __forceinline__ ushort f2bf(float f) {
  uint u = __float_as_uint(f);
  uint r = (u + 0x7FFFu + ((u >> 16) & 1u)) >> 16;
  return (ushort)r;
}

__device__ __forceinline__ ushort f2h(float f) {
  return __half_as_ushort(__float2half(f));
}
__device__ __forceinline__ float h2f(ushort u) {
  return __half2float(__ushort_as_half(u));
}

// wave-level exclusive scan of partials[0..nparts) -> per-lane excl value
__device__ __forceinline__ int wave_scan_partials(const int* __restrict__ partials,
                                                  int nparts, int lane) {
  int pv = (lane < nparts) ? partials[lane] : 0;
  int incl = pv;
#pragma unroll
  for (int d = 1; d < 64; d <<= 1) {
    int t = __shfl_up(incl, d, 64);
    if (lane >= d) incl += t;
  }
  return incl - pv;
}

// ---- Kernel W: weight fp32 -> Bt bf16; zero the 8 per-XCD count slices ----
__global__ void convert_w(const float* __restrict__ w, ushort* __restrict__ bt,
                          int* __restrict__ counts8, int nnodes) {
  const int idx = blockIdx.x * 256 + threadIdx.x;  // 0..65535
  if (idx < nnodes) {
#pragma unroll
    for (int s = 0; s < NXCD; ++s) counts8[s * nnodes + idx] = 0;
  }
  const int n = idx >> 8, k = idx & 255;
  const int h = n >> 6, c = n & 63;
  bt[idx] = f2bf(w[h * (N_IN_CH * OUT_CH) + k * OUT_CH + c]);
}

// ---- Kernel A: INTERLEAVED heterogeneous proj || count ---------------------
// Count path now uses NEAR (L2-local) atomics on per-XCD counter slices:
// slice x only ever receives atomics from XCD x (coherent in that L2), so the
// no-sc1 global_atomic_add never pays the far-coherence-point round trip that
// R16-R18 proved isn't contention/latency but (hypothesis) far-throughput.
__global__ __launch_bounds__(256) void proj_count(
    const float* __restrict__ x, const ushort* __restrict__ bt,
    const float* __restrict__ att_src, const float* __restrict__ att_dst,
    ushort* __restrict__ xh, float* __restrict__ asrc, float* __restrict__ adst,
    int nnodes, int nblocksA,
    const int* __restrict__ row, int* __restrict__ counts8,
    int* __restrict__ rank, int nedges) {
  __shared__ ushort at[HM * N_IN_CH];  // 16 KB (proj path only)
  const int tid = threadIdx.x;
  const int bid = blockIdx.x;
  const int g = bid / 5;
  const bool is_proj = (bid % 5 == 0) && (g < nblocksA);

  if (!is_proj) {  // ---- count path: 4k + (bid%5) - 1, bijective 0..eblk-1 --
    const int cb = (bid % 5 == 0) ? (4 * g)  // only when g >= nblocksA (tail)
                                  : (4 * g + (bid % 5) - 1);
    const int e = cb * 256 + tid;
    if (e < nedges) {
      const int r = row[e];
      uint xcc;
      asm("s_getreg_b32 %0, hwreg(HW_REG_XCC_ID)" : "=s"(xcc));
      xcc &= (NXCD - 1);
      int* ap = &counts8[(size_t)xcc * nnodes + r];
      int old;
      asm volatile(
          "global_atomic_add %0, %1, %2, off sc0\n\t"
          "s_waitcnt vmcnt(0)"
          : "=v"(old)
          : "v"(ap), "v"(1)
          : "memory");
      rank[e] = (int)((xcc << 16) | (uint)old);
    }
    return;
  }

  // ---- proj path: two 32-row halves sharing the 16KB LDS buffer ----
  const int wave = tid >> 6;
  const int lane = tid & 63;
  const int lmod = lane & 15;
  const int ldiv = lane >> 4;

  float atts[4], attd[4];
#pragma unroll
  for (int nt = 0; nt < 4; ++nt) {
    const int gcol = wave * 64 + nt * 16 + lmod;
    atts[nt] = att_src[gcol];
    attd[nt] = att_dst[gcol];
  }

  for (int h0 = 0; h0 < 2; ++h0) {
    const int n0 = g * BM + h0 * HM;

    {
      const int rsub = tid >> 6;
      const int cf = (tid & 63) * 4;
      const int cb2 = cf * 2;
#pragma unroll
      for (int it = 0; it < 8; ++it) {
        const int lr = it * 4 + rsub;          // local row 0..31
        const int grow = n0 + lr;
        float4 xv = make_float4(0.f, 0.f, 0.f, 0.f);
        if (grow < nnodes) xv = *(const float4*)&x[(size_t)grow * N_IN_CH + cf];
        ushort4 b;
        b.x = f2bf(xv.x); b.y = f2bf(xv.y); b.z = f2bf(xv.z); b.w = f2bf(xv.w);
        const int cbs = cb2 ^ ((lr & 7) << 4);
        *(ushort4*)((char*)at + lr * 512 + cbs) = b;
      }
    }
    __syncthreads();

    f32x4 acc[2][4];
#pragma unroll
    for (int mt = 0; mt < 2; ++mt)
#pragma unroll
      for (int nt = 0; nt < 4; ++nt) acc[mt][nt] = (f32x4){0.f, 0.f, 0.f, 0.f};

    for (int ks = 0; ks < 8; ++ks) {
      bf16x8 a[2], b[4];
#pragma unroll
      for (int mt = 0; mt < 2; ++mt) {
        const int lr = mt * 16 + lmod;
        const int kb = ks * 64 + ldiv * 16;
        const int cbs = kb ^ ((lr & 7) << 4);
        a[mt] = *(const bf16x8*)((const char*)at + lr * 512 + cbs);
      }
#pragma unroll
      for (int nt = 0; nt < 4; ++nt) {
        const int n = wave * 64 + nt * 16 + lmod;
        b[nt] = *(const bf16x8*)&bt[(size_t)n * N_IN_CH + ks * 32 + ldiv * 8];
      }
#pragma unroll
      for (int mt = 0; mt < 2; ++mt)
#pragma unroll
        for (int nt = 0; nt < 4; ++nt)
          acc[mt][nt] = __builtin_amdgcn_mfma_f32_16x16x32_bf16(
              a[mt], b[nt], acc[mt][nt], 0, 0, 0);
    }

#pragma unroll
    for (int mt = 0; mt < 2; ++mt) {
#pragma unroll
      for (int reg = 0; reg < 4; ++reg) {
        const int grow = n0 + mt * 16 + ldiv * 4 + reg;  // C/D row=(lane>>4)*4+reg
        const bool ok = grow < nnodes;
        float vs = 0.f, vd = 0.f;
#pragma unroll
        for (int nt = 0; nt < 4; ++nt) {
          const float v = acc[mt][nt][reg];
          if (ok) xh[(size_t)grow * N_OUT + wave * 64 + nt * 16 + lmod] = f2h(v);
          vs = fmaf(v, atts[nt], vs);
          vd = fmaf(v, attd[nt], vd);
        }
#pragma unroll
        for (int d = 1; d < 16; d <<= 1) {
          vs += __shfl_xor(vs, d, 64);
          vd += __shfl_xor(vd, d, 64);
        }
        if (lmod == 0 && ok) {
          asrc[grow * HEADS + wave] = vs;
          adst[grow * HEADS + wave] = vd;
        }
      }
    }
    __syncthreads();  // LDS reused by next half
  }
}

// -- scan1: fold 8 XCD slices -> per-XCD excl prefix (in place) + degree,
//    then block-local exclusive scan over degrees --------------------------
__global__ __launch_bounds__(SCAN_BLOCK) void scan1_kernel(
    int* __restrict__ counts8, int* __restrict__ offsets,
    int* __restrict__ partials, int n) {
  __shared__ int wsum[16];
  const int tid = threadIdx.x;
  const int lane = tid & 63;
  const int wid = tid >> 6;
  const int i = blockIdx.x * SCAN_BLOCK + tid;

  int v = 0;
  if (i < n) {
    int running = 0;
#pragma unroll
    for (int s = 0; s < NXCD; ++s) {
      const int h = counts8[s * n + i];
      counts8[s * n + i] = running;  // per-XCD exclusive prefix, in place
      running += h;
    }
    v = running;  // degree
  }

  int incl = v;
#pragma unroll
  for (int d = 1; d < 64; d <<= 1) {
    int t = __shfl_up(incl, d, 64);
    if (lane >= d) incl += t;
  }
  if (lane == 63) wsum[wid] = incl;
  __syncthreads();
  if (wid == 0) {
    int wv = (lane < 16) ? wsum[lane] : 0;
#pragma unroll
    for (int d = 1; d < 16; d <<= 1) {
      int t = __shfl_up(wv, d, 64);
      if (lane >= d) wv += t;
    }
    if (lane < 16) wsum[lane] = wv;
  }
  __syncthreads();
  const int wexcl = (wid == 0) ? 0 : wsum[wid - 1];
  if (i <= n) offsets[i] = wexcl + incl - v;
  if (tid == SCAN_BLOCK - 1) partials[blockIdx.x] = wsum[15];
}

// -- scatter: packed 16B edge record; pos = offsets + partials + xcdpre + rk -
__global__ void scatter_kernel(const int* __restrict__ row, const int* __restrict__ col,
                               const int* __restrict__ rank,
                               const int* __restrict__ offsets,
                               const int* __restrict__ counts8,
                               const int* __restrict__ partials, int nparts,
                               const float* __restrict__ asrc,
                               const float* __restrict__ adst,
                               uint4* __restrict__ erec, int nedges, int nnodes) {
  const int lane = threadIdx.x & 63;
  const int excl = wave_scan_partials(partials, nparts, lane);
  int e = blockIdx.x * blockDim.x + threadIdx.x;
  if (e < nedges) {
    const int r = row[e];
    const int c = col[e];
    const int rk = rank[e];
    const int xcc = (rk >> 16) & (NXCD - 1);
    const int pos = offsets[r] + __shfl(excl, r >> 10, 64) +
                    counts8[(size_t)xcc * nnodes + r] + (rk & 0xFFFF);
    const float4 s = *(const float4*)&asrc[r * 4];
    const float4 d = *(const float4*)&adst[c * 4];
    uint4 rec;
    rec.x = (uint)c;
    rec.y = (uint)f2h(__expf(lrelu(s.x + d.x))) |
            ((uint)f2h(__expf(lrelu(s.y + d.y))) << 16);
    rec.z = (uint)f2h(__expf(lrelu(s.z + d.z))) |
            ((uint)f2h(__expf(lrelu(s.w + d.w))) << 16);
    rec.w = 0u;
    erec[pos] = rec;
  }
}

// ------- gather: denominator folded into the weight reads (no shfl tree) ----
__global__ __launch_bounds__(256) void gather_kernel(
    const int* __restrict__ offsets,
    const int* __restrict__ partials, int nparts,
    const uint4* __restrict__ erec,
    const ushort* __restrict__ xh, const float* __restrict__ bias,
    float* __restrict__ out, int nnodes) {
  __shared__ float pbuf[4][64 * 4];
  const int wv = threadIdx.x >> 6;
  const int lane = threadIdx.x & 63;
  const int n = blockIdx.x * 4 + wv;
  if (n >= nnodes) return;
  const int excl = wave_scan_partials(partials, nparts, lane);
  const int off = offsets[n] + __shfl(excl, n >> 10, 64);
  const int end = offsets[n + 1] + __shfl(excl, (n + 1) >> 10, 64);
  const int deg = end - off;
  const int half = lane >> 5;        // 0: even edges, 1: odd edges
  const int ch8 = (lane & 31) * 8;   // this lane's 8 output channels
  const int hh = (lane & 31) >> 3;   // head owning those channels

  float wsum = 0.f;
  float a0 = 0.f, a1 = 0.f, a2 = 0.f, a3 = 0.f;
  float a4 = 0.f, a5 = 0.f, a6 = 0.f, a7 = 0.f;

  for (int b = 0; b < deg; b += 64) {
    const int cnt = min(64, deg - b);
    // one coalesced 16B load: source id + 4 precomputed f16 weights
    int cl_l = 0;
    float4 p = make_float4(0.f, 0.f, 0.f, 0.f);
    if (lane < cnt) {
      const uint4 rec = erec[off + b + lane];
      cl_l = (int)rec.x;
      p.x = h2f((ushort)(rec.y & 0xFFFFu));
      p.y = h2f((ushort)(rec.y >> 16));
      p.z = h2f((ushort)(rec.z & 0xFFFFu));
      p.w = h2f((ushort)(rec.z >> 16));
    }
    *(float4*)&pbuf[wv][lane * 4] = p;
    // same-wave LDS write->read ordered via lgkmcnt (no barrier needed)

    for (int j = 0; j < cnt; j += 16) {
      // distribute addresses via shuffles, issue payload loads immediately.
      // invalid tail slots carry cl=0 (safe read) and weight 0.
      int cq[8];
#pragma unroll
      for (int q = 0; q < 8; ++q) cq[q] = __shfl(cl_l, j + 2 * q + half, 64);
      uint4 xq[8];
#pragma unroll
      for (int q = 0; q < 8; ++q)
        xq[q] = *(const uint4*)&xh[(size_t)cq[q] * N_OUT + ch8];

      float wq[8];
#pragma unroll
      for (int q = 0; q < 8; ++q) wq[q] = pbuf[wv][(j + 2 * q + half) * 4 + hh];

#pragma unroll
      for (int q = 0; q < 8; ++q) {
        wsum += wq[q];
        a0 = fmaf(wq[q], h2f((ushort)(xq[q].x & 0xFFFFu)), a0);
        a1 = fmaf(wq[q], h2f((ushort)(xq[q].x >> 16)), a1);
        a2 = fmaf(wq[q], h2f((ushort)(xq[q].y & 0xFFFFu)), a2);
        a3 = fmaf(wq[q], h2f((ushort)(xq[q].y >> 16)), a3);
        a4 = fmaf(wq[q], h2f((ushort)(xq[q].z & 0xFFFFu)), a4);
        a5 = fmaf(wq[q], h2f((ushort)(xq[q].z >> 16)), a5);
        a6 = fmaf(wq[q], h2f((ushort)(xq[q].w & 0xFFFFu)), a6);
        a7 = fmaf(wq[q], h2f((ushort)(xq[q].w >> 16)), a7);
      }
    }
  }

  // combine the two edge-halves (both halves end with the full sums)
  a0 += __shfl_xor(a0, 32, 64);
  a1 += __shfl_xor(a1, 32, 64);
  a2 += __shfl_xor(a2, 32, 64);
  a3 += __shfl_xor(a3, 32, 64);
  a4 += __shfl_xor(a4, 32, 64);
  a5 += __shfl_xor(a5, 32, 64);
  a6 += __shfl_xor(a6, 32, 64);
  a7 += __shfl_xor(a7, 32, 64);
  wsum += __shfl_xor(wsum, 32, 64);

  const float invh = 1.f / fmaxf(wsum, 1e-16f);

  // each half writes 4 of the lane's 8 channels (fully coalesced 256 floats)
  const int wch = ch8 + half * 4;
  const float4 b4 = *(const float4*)&bias[wch];
  float4 o;
  o.x = fmaf(half ? a4 : a0, invh, b4.x);
  o.y = fmaf(half ? a5 : a1, invh, b4.y);
  o.z = fmaf(half ? a6 : a2, invh, b4.z);
  o.w = fmaf(half ? a7 : a3, invh, b4.w);
  *(float4*)&out[(size_t)n * N_OUT + wch] = o;
}

extern "C" void kernel_launch(void* const* d_in, const int* in_sizes, int n_in,
                              void* d_out, int out_size, void* d_ws, size_t ws_size,
                              hipStream_t stream) {
  const float* x        = (const float*)d_in[0];
  const int*   edge_idx = (const int*)d_in[1];
  const float* weight   = (const float*)d_in[2];
  const float* att_src  = (const float*)d_in[3];
  const float* att_dst  = (const float*)d_in[4];
  const float* bias     = (const float*)d_in[5];
  float* out = (float*)d_out;

  const int nnodes = in_sizes[0] / N_IN_CH;
  const int nedges = in_sizes[1] / 2;
  const int* row = edge_idx;            // destinations (segment index)
  const int* col = edge_idx + nedges;   // sources (features gathered)

  char* wsb = (char*)d_ws;
  size_t woff = 0;
  auto alloc = [&](size_t bytes) -> char* {
    char* p = wsb + woff;
    woff += (bytes + 255) & ~(size_t)255;
    return p;
  };
  ushort* xh    = (ushort*)alloc((size_t)nnodes * N_OUT * sizeof(ushort));
  ushort* bt    = (ushort*)alloc((size_t)N_OUT * N_IN_CH * sizeof(ushort));
  float* asrc   = (float*)alloc((size_t)nnodes * HEADS * sizeof(float));
  float* adst   = (float*)alloc((size_t)nnodes * HEADS * sizeof(float));
  int* counts8  = (int*)alloc((size_t)nnodes * NXCD * sizeof(int));
  int* offsets  = (int*)alloc((size_t)(nnodes + 1) * sizeof(int));
  int* partials = (int*)alloc(256 * sizeof(int));
  int* rank     = (int*)alloc((size_t)nedges * sizeof(int));
  uint4* erec   = (uint4*)alloc((size_t)nedges * sizeof(uint4));

  convert_w<<<256, 256, 0, stream>>>(weight, bt, counts8, nnodes);

  const int eblocks = (nedges + 255) / 256;                        // 3125
  const int nblocksA = (nnodes + BM - 1) / BM;                     // 782
  const int total = nblocksA + eblocks;                            // 3907
  proj_count<<<total, 256, 0, stream>>>(
      x, bt, att_src, att_dst, xh, asrc, adst, nnodes, nblocksA,
      row, counts8, rank, nedges);

  const int nscan = (nnodes + 1 + SCAN_BLOCK - 1) / SCAN_BLOCK;    // 49
  scan1_kernel<<<nscan, SCAN_BLOCK, 0, stream>>>(counts8, offsets, partials, nnodes);

  scatter_kernel<<<eblocks, 256, 0, stream>>>(row, col, rank, offsets, counts8,
                                              partials, nscan,
                                              asrc, adst, erec, nedges, nnodes);

  gather_kernel<<<(nnodes + 3) / 4, 256, 0, stream>>>(offsets, partials, nscan,
                                                      erec, xh, bias, out, nnodes);
}

// Round 20
// 149.742 us; speedup vs baseline: 1.1408x; 1.0318x over previous
//
#include <hip/hip_runtime.h>
#include <hip/hip_fp16.h>
#include <math.h>

#define N_IN_CH 256
#define N_OUT   256   // HEADS * OUT_CH
#define HEADS   4
#define OUT_CH  64
#define BM      64    // rows per proj block (two halves of HM)
#define HM      32    // half-tile rows -> 16KB LDS, 32 AGPR
#define SCAN_BLOCK 1024

typedef __attribute__((ext_vector_type(8))) short bf16x8;
typedef __attribute__((ext_vector_type(4))) float f32x4;

__device__ __forceinline__ float lrelu(float a) {
  return a >= 0.f ? a : 0.2f * a;
}

__device__ __forceinline__ ushort f2bf(float f) {
  uint u = __float_as_uint(f);
  uint r = (u + 0x7FFFu + ((u >> 16) & 1u)) >> 16;
  return (ushort)r;
}

__device__ __forceinline__ ushort f2h(float f) {
  return __half_as_ushort(__float2half(f));
}
__device__ __forceinline__ float h2f(ushort u) {
  return __half2float(__ushort_as_half(u));
}

// wave-level exclusive scan of partials[0..nparts) -> per-lane excl value
__device__ __forceinline__ int wave_scan_partials(const int* __restrict__ partials,
                                                  int nparts, int lane) {
  int pv = (lane < nparts) ? partials[lane] : 0;
  int incl = pv;
#pragma unroll
  for (int d = 1; d < 64; d <<= 1) {
    int t = __shfl_up(incl, d, 64);
    if (lane >= d) incl += t;
  }
  return incl - pv;
}

// -------- Kernel W: weight [H][K][C] fp32 -> Bt [N][K] bf16; zero counts ----
__global__ void convert_w(const float* __restrict__ w, ushort* __restrict__ bt,
                          int* __restrict__ counts, int nnodes) {
  const int idx = blockIdx.x * 256 + threadIdx.x;  // 0..65535
  if (idx < nnodes) counts[idx] = 0;
  const int n = idx >> 8, k = idx & 255;
  const int h = n >> 6, c = n & 63;
  bt[idx] = f2bf(w[h * (N_IN_CH * OUT_CH) + k * OUT_CH + c]);
}

// ---- Kernel A: INTERLEAVED heterogeneous proj || count (R15, session best) -
// Every 5th block is a proj block; each CU co-resides proj + count blocks so
// atomics hide under MFMA/staging stalls and vice versa. Count-cost probes
// (padding/slot-spread/fire-and-forget/XCD-local: R14,R16-R19) all null —
// this plain form is the measured optimum.
__global__ __launch_bounds__(256) void proj_count(
    const float* __restrict__ x, const ushort* __restrict__ bt,
    const float* __restrict__ att_src, const float* __restrict__ att_dst,
    ushort* __restrict__ xh, float* __restrict__ asrc, float* __restrict__ adst,
    int nnodes, int nblocksA,
    const int* __restrict__ row, int* __restrict__ counts,
    int* __restrict__ rank, int nedges) {
  __shared__ ushort at[HM * N_IN_CH];  // 16 KB (proj path only)
  const int tid = threadIdx.x;
  const int bid = blockIdx.x;
  const int g = bid / 5;
  const bool is_proj = (bid % 5 == 0) && (g < nblocksA);

  if (!is_proj) {  // ---- count path: 4k + (bid%5) - 1, bijective 0..eblk-1 --
    const int cb = (bid % 5 == 0) ? (4 * g)  // only when g >= nblocksA (tail)
                                  : (4 * g + (bid % 5) - 1);
    const int e = cb * 256 + tid;
    if (e < nedges) rank[e] = atomicAdd(&counts[row[e]], 1);
    return;
  }

  // ---- proj path: two 32-row halves sharing the 16KB LDS buffer ----
  const int wave = tid >> 6;
  const int lane = tid & 63;
  const int lmod = lane & 15;
  const int ldiv = lane >> 4;

  float atts[4], attd[4];
#pragma unroll
  for (int nt = 0; nt < 4; ++nt) {
    const int gcol = wave * 64 + nt * 16 + lmod;
    atts[nt] = att_src[gcol];
    attd[nt] = att_dst[gcol];
  }

  for (int h0 = 0; h0 < 2; ++h0) {
    const int n0 = g * BM + h0 * HM;

    {
      const int rsub = tid >> 6;
      const int cf = (tid & 63) * 4;
      const int cb2 = cf * 2;
#pragma unroll
      for (int it = 0; it < 8; ++it) {
        const int lr = it * 4 + rsub;          // local row 0..31
        const int grow = n0 + lr;
        float4 xv = make_float4(0.f, 0.f, 0.f, 0.f);
        if (grow < nnodes) xv = *(const float4*)&x[(size_t)grow * N_IN_CH + cf];
        ushort4 b;
        b.x = f2bf(xv.x); b.y = f2bf(xv.y); b.z = f2bf(xv.z); b.w = f2bf(xv.w);
        const int cbs = cb2 ^ ((lr & 7) << 4);
        *(ushort4*)((char*)at + lr * 512 + cbs) = b;
      }
    }
    __syncthreads();

    f32x4 acc[2][4];
#pragma unroll
    for (int mt = 0; mt < 2; ++mt)
#pragma unroll
      for (int nt = 0; nt < 4; ++nt) acc[mt][nt] = (f32x4){0.f, 0.f, 0.f, 0.f};

    for (int ks = 0; ks < 8; ++ks) {
      bf16x8 a[2], b[4];
#pragma unroll
      for (int mt = 0; mt < 2; ++mt) {
        const int lr = mt * 16 + lmod;
        const int kb = ks * 64 + ldiv * 16;
        const int cbs = kb ^ ((lr & 7) << 4);
        a[mt] = *(const bf16x8*)((const char*)at + lr * 512 + cbs);
      }
#pragma unroll
      for (int nt = 0; nt < 4; ++nt) {
        const int n = wave * 64 + nt * 16 + lmod;
        b[nt] = *(const bf16x8*)&bt[(size_t)n * N_IN_CH + ks * 32 + ldiv * 8];
      }
#pragma unroll
      for (int mt = 0; mt < 2; ++mt)
#pragma unroll
        for (int nt = 0; nt < 4; ++nt)
          acc[mt][nt] = __builtin_amdgcn_mfma_f32_16x16x32_bf16(
              a[mt], b[nt], acc[mt][nt], 0, 0, 0);
    }

#pragma unroll
    for (int mt = 0; mt < 2; ++mt) {
#pragma unroll
      for (int reg = 0; reg < 4; ++reg) {
        const int grow = n0 + mt * 16 + ldiv * 4 + reg;  // C/D row=(lane>>4)*4+reg
        const bool ok = grow < nnodes;
        float vs = 0.f, vd = 0.f;
#pragma unroll
        for (int nt = 0; nt < 4; ++nt) {
          const float v = acc[mt][nt][reg];
          if (ok) xh[(size_t)grow * N_OUT + wave * 64 + nt * 16 + lmod] = f2h(v);
          vs = fmaf(v, atts[nt], vs);
          vd = fmaf(v, attd[nt], vd);
        }
#pragma unroll
        for (int d = 1; d < 16; d <<= 1) {
          vs += __shfl_xor(vs, d, 64);
          vd += __shfl_xor(vd, d, 64);
        }
        if (lmod == 0 && ok) {
          asrc[grow * HEADS + wave] = vs;
          adst[grow * HEADS + wave] = vd;
        }
      }
    }
    __syncthreads();  // LDS reused by next half
  }
}

// ---------------- scan1: block-local exclusive scan over n+1 elems ----------
__global__ __launch_bounds__(SCAN_BLOCK) void scan1_kernel(
    const int* __restrict__ counts, int* __restrict__ offsets,
    int* __restrict__ partials, int n) {
  __shared__ int wsum[16];
  const int tid = threadIdx.x;
  const int lane = tid & 63;
  const int wid = tid >> 6;
  const int i = blockIdx.x * SCAN_BLOCK + tid;
  int v = (i < n) ? counts[i] : 0;
  int incl = v;
#pragma unroll
  for (int d = 1; d < 64; d <<= 1) {
    int t = __shfl_up(incl, d, 64);
    if (lane >= d) incl += t;
  }
  if (lane == 63) wsum[wid] = incl;
  __syncthreads();
  if (wid == 0) {
    int wv = (lane < 16) ? wsum[lane] : 0;
#pragma unroll
    for (int d = 1; d < 16; d <<= 1) {
      int t = __shfl_up(wv, d, 64);
      if (lane >= d) wv += t;
    }
    if (lane < 16) wsum[lane] = wv;
  }
  __syncthreads();
  const int wexcl = (wid == 0) ? 0 : wsum[wid - 1];
  if (i <= n) offsets[i] = wexcl + incl - v;
  if (tid == SCAN_BLOCK - 1) partials[blockIdx.x] = wsum[15];
}

// -- scatter: packed 16B edge record {col, 4xf16 weights}; inline scan2 ------
__global__ void scatter_kernel(const int* __restrict__ row, const int* __restrict__ col,
                               const int* __restrict__ rank,
                               const int* __restrict__ offsets,
                               const int* __restrict__ partials, int nparts,
                               const float* __restrict__ asrc,
                               const float* __restrict__ adst,
                               uint4* __restrict__ erec, int nedges) {
  const int lane = threadIdx.x & 63;
  const int excl = wave_scan_partials(partials, nparts, lane);
  int e = blockIdx.x * blockDim.x + threadIdx.x;
  if (e < nedges) {
    const int r = row[e];
    const int c = col[e];
    const int pos = offsets[r] + __shfl(excl, r >> 10, 64) + rank[e];
    const float4 s = *(const float4*)&asrc[r * 4];
    const float4 d = *(const float4*)&adst[c * 4];
    uint4 rec;
    rec.x = (uint)c;
    rec.y = (uint)f2h(__expf(lrelu(s.x + d.x))) |
            ((uint)f2h(__expf(lrelu(s.y + d.y))) << 16);
    rec.z = (uint)f2h(__expf(lrelu(s.z + d.z))) |
            ((uint)f2h(__expf(lrelu(s.w + d.w))) << 16);
    rec.w = 0u;
    erec[pos] = rec;
  }
}

// ------- gather: denominator folded into the weight reads (wsum-fold) -------
// Each lane's wq[8] per chunk IS its half's edge weights for its head:
// denominator = sum(wq) + shfl_xor(,32). Strictly less work than the
// 4-accumulator + 24-shuffle tree it replaces.
__global__ __launch_bounds__(256) void gather_kernel(
    const int* __restrict__ offsets,
    const int* __restrict__ partials, int nparts,
    const uint4* __restrict__ erec,
    const ushort* __restrict__ xh, const float* __restrict__ bias,
    float* __restrict__ out, int nnodes) {
  __shared__ float pbuf[4][64 * 4];
  const int wv = threadIdx.x >> 6;
  const int lane = threadIdx.x & 63;
  const int n = blockIdx.x * 4 + wv;
  if (n >= nnodes) return;
  const int excl = wave_scan_partials(partials, nparts, lane);
  const int off = offsets[n] + __shfl(excl, n >> 10, 64);
  const int end = offsets[n + 1] + __shfl(excl, (n + 1) >> 10, 64);
  const int deg = end - off;
  const int half = lane >> 5;        // 0: even edges, 1: odd edges
  const int ch8 = (lane & 31) * 8;   // this lane's 8 output channels
  const int hh = (lane & 31) >> 3;   // head owning those channels

  float wsum = 0.f;
  float a0 = 0.f, a1 = 0.f, a2 = 0.f, a3 = 0.f;
  float a4 = 0.f, a5 = 0.f, a6 = 0.f, a7 = 0.f;

  for (int b = 0; b < deg; b += 64) {
    const int cnt = min(64, deg - b);
    // one coalesced 16B load: source id + 4 precomputed f16 weights
    int cl_l = 0;
    float4 p = make_float4(0.f, 0.f, 0.f, 0.f);
    if (lane < cnt) {
      const uint4 rec = erec[off + b + lane];
      cl_l = (int)rec.x;
      p.x = h2f((ushort)(rec.y & 0xFFFFu));
      p.y = h2f((ushort)(rec.y >> 16));
      p.z = h2f((ushort)(rec.z & 0xFFFFu));
      p.w = h2f((ushort)(rec.z >> 16));
    }
    *(float4*)&pbuf[wv][lane * 4] = p;
    // same-wave LDS write->read ordered via lgkmcnt (no barrier needed)

    for (int j = 0; j < cnt; j += 16) {
      // distribute addresses via shuffles, issue payload loads immediately.
      // invalid tail slots carry cl=0 (safe read) and weight 0.
      int cq[8];
#pragma unroll
      for (int q = 0; q < 8; ++q) cq[q] = __shfl(cl_l, j + 2 * q + half, 64);
      uint4 xq[8];
#pragma unroll
      for (int q = 0; q < 8; ++q)
        xq[q] = *(const uint4*)&xh[(size_t)cq[q] * N_OUT + ch8];

      float wq[8];
#pragma unroll
      for (int q = 0; q < 8; ++q) wq[q] = pbuf[wv][(j + 2 * q + half) * 4 + hh];

#pragma unroll
      for (int q = 0; q < 8; ++q) {
        wsum += wq[q];
        a0 = fmaf(wq[q], h2f((ushort)(xq[q].x & 0xFFFFu)), a0);
        a1 = fmaf(wq[q], h2f((ushort)(xq[q].x >> 16)), a1);
        a2 = fmaf(wq[q], h2f((ushort)(xq[q].y & 0xFFFFu)), a2);
        a3 = fmaf(wq[q], h2f((ushort)(xq[q].y >> 16)), a3);
        a4 = fmaf(wq[q], h2f((ushort)(xq[q].z & 0xFFFFu)), a4);
        a5 = fmaf(wq[q], h2f((ushort)(xq[q].z >> 16)), a5);
        a6 = fmaf(wq[q], h2f((ushort)(xq[q].w & 0xFFFFu)), a6);
        a7 = fmaf(wq[q], h2f((ushort)(xq[q].w >> 16)), a7);
      }
    }
  }

  // combine the two edge-halves (both halves end with the full sums)
  a0 += __shfl_xor(a0, 32, 64);
  a1 += __shfl_xor(a1, 32, 64);
  a2 += __shfl_xor(a2, 32, 64);
  a3 += __shfl_xor(a3, 32, 64);
  a4 += __shfl_xor(a4, 32, 64);
  a5 += __shfl_xor(a5, 32, 64);
  a6 += __shfl_xor(a6, 32, 64);
  a7 += __shfl_xor(a7, 32, 64);
  wsum += __shfl_xor(wsum, 32, 64);

  const float invh = 1.f / fmaxf(wsum, 1e-16f);

  // each half writes 4 of the lane's 8 channels (fully coalesced 256 floats)
  const int wch = ch8 + half * 4;
  const float4 b4 = *(const float4*)&bias[wch];
  float4 o;
  o.x = fmaf(half ? a4 : a0, invh, b4.x);
  o.y = fmaf(half ? a5 : a1, invh, b4.y);
  o.z = fmaf(half ? a6 : a2, invh, b4.z);
  o.w = fmaf(half ? a7 : a3, invh, b4.w);
  *(float4*)&out[(size_t)n * N_OUT + wch] = o;
}

extern "C" void kernel_launch(void* const* d_in, const int* in_sizes, int n_in,
                              void* d_out, int out_size, void* d_ws, size_t ws_size,
                              hipStream_t stream) {
  const float* x        = (const float*)d_in[0];
  const int*   edge_idx = (const int*)d_in[1];
  const float* weight   = (const float*)d_in[2];
  const float* att_src  = (const float*)d_in[3];
  const float* att_dst  = (const float*)d_in[4];
  const float* bias     = (const float*)d_in[5];
  float* out = (float*)d_out;

  const int nnodes = in_sizes[0] / N_IN_CH;
  const int nedges = in_sizes[1] / 2;
  const int* row = edge_idx;            // destinations (segment index)
  const int* col = edge_idx + nedges;   // sources (features gathered)

  char* wsb = (char*)d_ws;
  size_t woff = 0;
  auto alloc = [&](size_t bytes) -> char* {
    char* p = wsb + woff;
    woff += (bytes + 255) & ~(size_t)255;
    return p;
  };
  ushort* xh    = (ushort*)alloc((size_t)nnodes * N_OUT * sizeof(ushort));
  ushort* bt    = (ushort*)alloc((size_t)N_OUT * N_IN_CH * sizeof(ushort));
  float* asrc   = (float*)alloc((size_t)nnodes * HEADS * sizeof(float));
  float* adst   = (float*)alloc((size_t)nnodes * HEADS * sizeof(float));
  int* counts   = (int*)alloc((size_t)nnodes * sizeof(int));
  int* offsets  = (int*)alloc((size_t)(nnodes + 1) * sizeof(int));
  int* partials = (int*)alloc(256 * sizeof(int));
  int* rank     = (int*)alloc((size_t)nedges * sizeof(int));
  uint4* erec   = (uint4*)alloc((size_t)nedges * sizeof(uint4));

  convert_w<<<256, 256, 0, stream>>>(weight, bt, counts, nnodes);

  const int eblocks = (nedges + 255) / 256;                        // 3125
  const int nblocksA = (nnodes + BM - 1) / BM;                     // 782
  const int total = nblocksA + eblocks;                            // 3907
  proj_count<<<total, 256, 0, stream>>>(
      x, bt, att_src, att_dst, xh, asrc, adst, nnodes, nblocksA,
      row, counts, rank, nedges);

  const int nscan = (nnodes + 1 + SCAN_BLOCK - 1) / SCAN_BLOCK;    // 49
  scan1_kernel<<<nscan, SCAN_BLOCK, 0, stream>>>(counts, offsets, partials, nnodes);

  scatter_kernel<<<eblocks, 256, 0, stream>>>(row, col, rank, offsets,
                                              partials, nscan,
                                              asrc, adst, erec, nedges);

  gather_kernel<<<(nnodes + 3) / 4, 256, 0, stream>>>(offsets, partials, nscan,
                                                      erec, xh, bias, out, nnodes);
}